// Round 7
// baseline (299.215 us; speedup 1.0000x reference)
//
#include <hip/hip_runtime.h>

#define IN_F 128
#define OUT_F 32
#define XS_LD 132   // 128 + 4 pad: vf4-aligned (132*4 = 33*16) and 8 wave-rows
                    // tile all 32 banks exactly once -> conflict-free b128.

typedef float vf4 __attribute__((ext_vector_type(4)));
typedef float vf2 __attribute__((ext_vector_type(2)));
typedef int   vi2 __attribute__((ext_vector_type(2)));
typedef _Float16 hf4 __attribute__((ext_vector_type(4)));
typedef _Float16 hf8 __attribute__((ext_vector_type(8)));

// ---------------------------------------------------------------------------
// Kernel 1: z = x @ W + b   (100000 x 128) * (128 x 32)   [UNCHANGED from r5]
// Conflict-free broadcast LDS reads; fp16 z epilogue (6.4 MB table).
// ---------------------------------------------------------------------------
__global__ __launch_bounds__(256) void zgemm_kernel(
    const float* __restrict__ x, const float* __restrict__ W,
    const float* __restrict__ b, _Float16* __restrict__ zh, int n_nodes)
{
    __shared__ float xs[64 * XS_LD];     // 33.8 KB (padded)
    __shared__ float Ws[IN_F * OUT_F];   // 16 KB, row-major as in global
    __shared__ float bs[OUT_F];

    const int t = threadIdx.x;
    const int row0 = blockIdx.x * 64;
    const int rows = min(64, n_nodes - row0);

    {
        const vf4* Wv = (const vf4*)W;
        vf4* Wsv = (vf4*)Ws;
        #pragma unroll
        for (int i = 0; i < 4; ++i)
            Wsv[t + i * 256] = Wv[t + i * 256];
        if (t < OUT_F) bs[t] = b[t];
    }
    {
        const vf4* xv = (const vf4*)(x + (size_t)row0 * IN_F);
        const int nv = rows * (IN_F / 4);
        for (int i = t; i < nv; i += 256) {
            const int row = i >> 5;
            const int kk  = i & 31;
            *(vf4*)(xs + row * XS_LD + (kk << 2)) = xv[i];
        }
    }
    __syncthreads();

    const int cg  = t & 7;
    const int rgg = t >> 3;
    const int c0  = cg << 2;

    vf4 acc0 = {0.f, 0.f, 0.f, 0.f};
    vf4 acc1 = {0.f, 0.f, 0.f, 0.f};

    #pragma unroll 4
    for (int k4 = 0; k4 < IN_F / 4; ++k4) {
        const vf4 xa = *(const vf4*)(xs + rgg * XS_LD + (k4 << 2));
        const vf4 xb = *(const vf4*)(xs + (rgg + 32) * XS_LD + (k4 << 2));
        const vf4 w0 = *(const vf4*)(Ws + ((k4 << 2) + 0) * OUT_F + c0);
        const vf4 w1 = *(const vf4*)(Ws + ((k4 << 2) + 1) * OUT_F + c0);
        const vf4 w2 = *(const vf4*)(Ws + ((k4 << 2) + 2) * OUT_F + c0);
        const vf4 w3 = *(const vf4*)(Ws + ((k4 << 2) + 3) * OUT_F + c0);

        acc0 += xa.x * w0;  acc0 += xa.y * w1;
        acc0 += xa.z * w2;  acc0 += xa.w * w3;
        acc1 += xb.x * w0;  acc1 += xb.y * w1;
        acc1 += xb.z * w2;  acc1 += xb.w * w3;
    }

    const vf4 bb = *(const vf4*)(bs + c0);
    const vf4 r0 = acc0 + bb;
    const vf4 r1 = acc1 + bb;

    if (rgg < rows) {
        hf4 h = { (_Float16)r0.x, (_Float16)r0.y, (_Float16)r0.z, (_Float16)r0.w };
        *(hf4*)(zh + (size_t)(row0 + rgg) * OUT_F + c0) = h;
    }
    if (rgg + 32 < rows) {
        hf4 h = { (_Float16)r1.x, (_Float16)r1.y, (_Float16)r1.z, (_Float16)r1.w };
        *(hf4*)(zh + (size_t)(row0 + rgg + 32) * OUT_F + c0) = h;
    }
}

// ---------------------------------------------------------------------------
// Kernel 2: out[e][:] = vals[e] * (z[rows[e]][:] + z[cols[e]][:]), z fp16.
// ILP=2 probe (same as round-6 intent, ext-vector types for the NT builtins):
// each thread owns an edge PAIR at 4 lanes/pair-slot; vi2/vf2 stream loads
// (half the stream transactions), 4 independent 16 B z-gathers in flight,
// 12.5k blocks. Each 4-thread group writes 256 B contiguous; NT policy kept.
// Discriminating probe: neutral => edge already at its traffic floor
// (2-fill world); big drop => latency/dispatch world.
// ---------------------------------------------------------------------------
__global__ __launch_bounds__(256) void edge_kernel(
    const int* __restrict__ erows, const int* __restrict__ ecols,
    const float* __restrict__ evals, const _Float16* __restrict__ zh,
    float* __restrict__ out, int n_edges)
{
    const size_t g = (size_t)blockIdx.x * 256 + threadIdx.x;
    const size_t p = g >> 2;              // pair index
    const size_t e0 = p << 1;
    if (e0 >= (size_t)n_edges) return;
    const int coff = (int)(g & 3) << 3;   // 0, 8, 16, 24

    // paired index/value streams: one 8B load each (2p even -> 8B aligned)
    const vi2 rr = __builtin_nontemporal_load((const vi2*)(erows + e0));
    const vi2 cc = __builtin_nontemporal_load((const vi2*)(ecols + e0));
    const vf2 ww = __builtin_nontemporal_load((const vf2*)(evals + e0));

    const bool has1 = (e0 + 1) < (size_t)n_edges;

    // 4 independent gathers (16 B each) — all issued before any use.
    const hf8 zr0 = *(const hf8*)(zh + (size_t)rr.x * OUT_F + coff);
    const hf8 zc0 = *(const hf8*)(zh + (size_t)cc.x * OUT_F + coff);
    const hf8 zr1 = has1 ? *(const hf8*)(zh + (size_t)rr.y * OUT_F + coff) : hf8{};
    const hf8 zc1 = has1 ? *(const hf8*)(zh + (size_t)cc.y * OUT_F + coff) : hf8{};

    vf4 a0, a1;
    a0.x = ww.x * ((float)zr0[0] + (float)zc0[0]);
    a0.y = ww.x * ((float)zr0[1] + (float)zc0[1]);
    a0.z = ww.x * ((float)zr0[2] + (float)zc0[2]);
    a0.w = ww.x * ((float)zr0[3] + (float)zc0[3]);
    a1.x = ww.x * ((float)zr0[4] + (float)zc0[4]);
    a1.y = ww.x * ((float)zr0[5] + (float)zc0[5]);
    a1.z = ww.x * ((float)zr0[6] + (float)zc0[6]);
    a1.w = ww.x * ((float)zr0[7] + (float)zc0[7]);

    float* op0 = out + e0 * OUT_F + coff;
    __builtin_nontemporal_store(a0, (vf4*)op0);
    __builtin_nontemporal_store(a1, (vf4*)(op0 + 4));

    if (has1) {
        vf4 b0, b1;
        b0.x = ww.y * ((float)zr1[0] + (float)zc1[0]);
        b0.y = ww.y * ((float)zr1[1] + (float)zc1[1]);
        b0.z = ww.y * ((float)zr1[2] + (float)zc1[2]);
        b0.w = ww.y * ((float)zr1[3] + (float)zc1[3]);
        b1.x = ww.y * ((float)zr1[4] + (float)zc1[4]);
        b1.y = ww.y * ((float)zr1[5] + (float)zc1[5]);
        b1.z = ww.y * ((float)zr1[6] + (float)zc1[6]);
        b1.w = ww.y * ((float)zr1[7] + (float)zc1[7]);

        float* op1 = out + (e0 + 1) * OUT_F + coff;
        __builtin_nontemporal_store(b0, (vf4*)op1);
        __builtin_nontemporal_store(b1, (vf4*)(op1 + 4));
    }
}

extern "C" void kernel_launch(void* const* d_in, const int* in_sizes, int n_in,
                              void* d_out, int out_size, void* d_ws, size_t ws_size,
                              hipStream_t stream)
{
    const float* x  = (const float*)d_in[0];   // (100000, 128)
    const float* W  = (const float*)d_in[1];   // (128, 32)
    const float* b  = (const float*)d_in[2];   // (32,)
    const int* erow = (const int*)d_in[3];     // (E,) int32
    const int* ecol = (const int*)d_in[4];     // (E,) int32
    const float* ev = (const float*)d_in[5];   // (E,)

    const int n_nodes = in_sizes[0] / IN_F;
    const int n_edges = in_sizes[3];

    _Float16* zh = (_Float16*)d_ws;            // n_nodes*32*2 = 6.4 MB scratch
    float* out = (float*)d_out;                // (E, 32)

    const int gemm_blocks = (n_nodes + 63) / 64;
    zgemm_kernel<<<gemm_blocks, 256, 0, stream>>>(x, W, b, zh, n_nodes);

    const size_t n_pairs = ((size_t)n_edges + 1) >> 1;
    const size_t total_thr = n_pairs * 4;
    const int edge_blocks = (int)((total_thr + 255) / 256);
    edge_kernel<<<edge_blocks, 256, 0, stream>>>(erow, ecol, ev, zh, out, n_edges);
}